// Round 12
// baseline (362.445 us; speedup 1.0000x reference)
//
#include <hip/hip_runtime.h>
#include <stdint.h>
#include <math.h>

typedef unsigned short u16;
typedef __attribute__((ext_vector_type(8))) __bf16 bf16x8;
typedef __attribute__((ext_vector_type(4))) float f32x4;
typedef __attribute__((ext_vector_type(16))) float f32x16;

#define NB 16
#define NSQ 512
#define NSE 512
#define ND 512
#define NH 8
#define NDH 64
#define NDFF 2048

__device__ __forceinline__ u16 f2b(float f) {
  uint32_t u = __float_as_uint(f);
  u = (u + 0x7FFFu + ((u >> 16) & 1u)) >> 16;
  return (u16)u;
}
__device__ __forceinline__ float b2f(uint32_t h) {
  return __uint_as_float(h << 16);
}

// async global->LDS, 16B per lane; LDS dest = wave-uniform base + lane*16
__device__ __forceinline__ void gl_lds16(const u16* g, u16* l) {
  __builtin_amdgcn_global_load_lds(
      (const __attribute__((address_space(1))) void*)g,
      (__attribute__((address_space(3))) void*)l, 16, 0, 0);
}

// ---------------- fused prep: 3 casts + 10 weight transposes, ONE dispatch ----
struct Prep {
  const float *x, *fc, *ff;
  u16 *xb, *fcb, *ffb;
  const float* w8[8];
  u16* o8[8];
  const float *w1, *w2;
  u16 *w1t, *w2t;
};

__device__ __forceinline__ void tr32(const float* __restrict__ W,
                                     u16* __restrict__ Wt, int K, int N, int bx,
                                     int by, float (*t)[33]) {
  const int tid = threadIdx.x, tx = tid & 31, ty = tid >> 5;
  const int n0 = bx * 32, k0 = by * 32;
#pragma unroll
  for (int i = 0; i < 32; i += 8)
    t[ty + i][tx] = W[(size_t)(k0 + ty + i) * N + n0 + tx];
  __syncthreads();
#pragma unroll
  for (int i = 0; i < 32; i += 8)
    Wt[(size_t)(n0 + ty + i) * K + k0 + tx] = f2b(t[tx][ty + i]);
}

__global__ void k_prep(Prep p) {
  __shared__ float t[32][33];
  const int blk = blockIdx.x;
  if (blk < 6144) {  // 3 activation casts, 8 elems/thread
    const int plane = blk >> 11;
    const float* src = plane == 0 ? p.x : (plane == 1 ? p.fc : p.ff);
    u16* dst = plane == 0 ? p.xb : (plane == 1 ? p.fcb : p.ffb);
    const int i = (blk & 2047) * 256 + threadIdx.x;
    const float4* q = (const float4*)(src + (size_t)i * 8);
    float4 v0 = q[0], v1 = q[1];
    uint4 o;
    o.x = (uint32_t)f2b(v0.x) | ((uint32_t)f2b(v0.y) << 16);
    o.y = (uint32_t)f2b(v0.z) | ((uint32_t)f2b(v0.w) << 16);
    o.z = (uint32_t)f2b(v1.x) | ((uint32_t)f2b(v1.y) << 16);
    o.w = (uint32_t)f2b(v1.z) | ((uint32_t)f2b(v1.w) << 16);
    *(uint4*)(dst + (size_t)i * 8) = o;
  } else if (blk < 8192) {  // 8 attention weights 512x512
    const int b2 = blk - 6144, z = b2 >> 8, bi = b2 & 255;
    tr32(p.w8[z], p.o8[z], 512, 512, bi & 15, bi >> 4, t);
  } else if (blk < 9216) {  // ffn_w1 [512,2048]
    const int b2 = blk - 8192;
    tr32(p.w1, p.w1t, 512, 2048, b2 & 63, b2 >> 6, t);
  } else {  // ffn_w2 [2048,512]
    const int b2 = blk - 9216;
    tr32(p.w2, p.w2t, 2048, 512, b2 & 15, b2 >> 4, t);
  }
}

// ---------------- GEMM core: m97 staging + 32x32x16 MFMA ----------------------
// Staging/barriers identical to the r11-proven structure; only the MFMA shape
// changes: per wave per K-step 16x 16x16x32 -> 8/16x 32x32x16 (half the
// instruction count, same ds_read count). A/B frags use identical lane wiring
// (row=lane&31, k=(lane>>5)*8+j) so any HW k-permutation cancels; C/D mapping
// col=lane&31, row=(reg&3)+8*(reg>>2)+4*(lane>>5) [HW-verified m74/m101].
enum { EPI_GELU = 2, EPI_RELU = 3, EPI_NONE = 4 };

template <int BM>
__device__ __forceinline__ void gemm_core(const u16* __restrict__ A,
                                          const u16* __restrict__ Bt, int K,
                                          int brow, int bcol, u16* As, u16* Bs,
                                          f32x16 (&acc)[BM / 64][2]) {
  const int tid = threadIdx.x, lane = tid & 63, wid = tid >> 6;
  const int wr = wid >> 1, wc = wid & 1;
  const int l31 = lane & 31, g5 = lane >> 5;
  const int sc8 = (lane & 7) * 8;
  const int srow = wid * 8 + (lane >> 3);
  const int nt = K >> 6;
  for (int t = 0; t < nt; ++t) {
    const int k0 = t << 6;
    if (t) __syncthreads();
#pragma unroll
    for (int v = 0; v < BM / 32; ++v)
      gl_lds16(A + (size_t)(brow + v * 32 + srow) * K + k0 + sc8,
               As + (v * 32 + wid * 8) * 64);
#pragma unroll
    for (int v = 0; v < 4; ++v)
      gl_lds16(Bt + (size_t)(bcol + v * 32 + srow) * K + k0 + sc8,
               Bs + (v * 32 + wid * 8) * 64);
    __syncthreads();
#pragma unroll
    for (int kk = 0; kk < 4; ++kk) {
      bf16x8 af[BM / 64], bfr[2];
#pragma unroll
      for (int m = 0; m < BM / 64; ++m)
        af[m] = *(const bf16x8*)(As + (wr * (BM / 2) + m * 32 + l31) * 64 +
                                 kk * 16 + g5 * 8);
#pragma unroll
      for (int n = 0; n < 2; ++n)
        bfr[n] = *(const bf16x8*)(Bs + (wc * 64 + n * 32 + l31) * 64 +
                                  kk * 16 + g5 * 8);
#pragma unroll
      for (int m = 0; m < BM / 64; ++m)
#pragma unroll
        for (int n = 0; n < 2; ++n)
          acc[m][n] =
              __builtin_amdgcn_mfma_f32_32x32x16_bf16(af[m], bfr[n], acc[m][n], 0, 0, 0);
    }
  }
}

template <int BM, int EPI>
__global__ __launch_bounds__(256, 3) void k_gemm(
    const u16* __restrict__ A, const u16* __restrict__ Bt,
    const float* __restrict__ bias, u16* __restrict__ out, int K, int N) {
  __shared__ u16 As[BM * 64];
  __shared__ u16 Bs[128 * 64];
  f32x16 acc[BM / 64][2] = {};
  const int brow = blockIdx.x * BM, bcol = blockIdx.y * 128;
  gemm_core<BM>(A, Bt, K, brow, bcol, As, Bs, acc);
  const int lane = threadIdx.x & 63, wid = threadIdx.x >> 6;
  const int wr = wid >> 1, wc = wid & 1, l31 = lane & 31, g5 = lane >> 5;
#pragma unroll
  for (int m = 0; m < BM / 64; ++m) {
    const int r0 = brow + wr * (BM / 2) + m * 32 + g5 * 4;
#pragma unroll
    for (int n = 0; n < 2; ++n) {
      const int col = bcol + wc * 64 + n * 32 + l31;
      const float bv = bias[col];
#pragma unroll
      for (int reg = 0; reg < 16; ++reg) {
        const int r = r0 + (reg & 3) + 8 * (reg >> 2);
        float vv = acc[m][n][reg] + bv;
        if (EPI == EPI_GELU) vv = 0.5f * vv * (1.0f + erff(vv * 0.70710678118654752f));
        if (EPI == EPI_RELU) vv = fmaxf(vv, 0.0f);
        out[(size_t)r * N + col] = f2b(vv);
      }
    }
  }
}

// fused Q/K/V projection: blockIdx.z picks weight/output
struct QKV {
  const u16* A[3];
  const u16* Bt[3];
  const float* bias[3];
  u16* out[3];
};
__global__ __launch_bounds__(256, 3) void k_gemm_qkv(QKV p) {
  const int z = blockIdx.z;
  __shared__ u16 As[128 * 64];
  __shared__ u16 Bs[128 * 64];
  f32x16 acc[2][2] = {};
  const int brow = blockIdx.x * 128, bcol = blockIdx.y * 128;
  gemm_core<128>(p.A[z], p.Bt[z], 512, brow, bcol, As, Bs, acc);
  const int lane = threadIdx.x & 63, wid = threadIdx.x >> 6;
  const int wr = wid >> 1, wc = wid & 1, l31 = lane & 31, g5 = lane >> 5;
  const float* bias = p.bias[z];
  u16* out = p.out[z];
#pragma unroll
  for (int m = 0; m < 2; ++m) {
    const int r0 = brow + wr * 64 + m * 32 + g5 * 4;
#pragma unroll
    for (int n = 0; n < 2; ++n) {
      const int col = bcol + wc * 64 + n * 32 + l31;
      const float bv = bias[col];
      const int h = col >> 6, d = col & 63;
#pragma unroll
      for (int reg = 0; reg < 16; ++reg) {
        const int r = r0 + (reg & 3) + 8 * (reg >> 2);
        const int b = r >> 9, s = r & 511;
        const float vv = acc[m][n][reg] + bv;
        if (z < 2)
          out[((size_t)(b * NH + h) * NSQ + s) * NDH + d] = f2b(vv);
        else
          out[((size_t)(b * NH + h) * NDH + d) * NSE + s] = f2b(vv);
      }
    }
  }
}

// ---------------- fused attention: logits + softmax + PV ----------------------
// r11-proven version, unchanged: K double-buffer (1 barrier/tile pass A;
// prefetch ages under computeS), balanced causal remap, normal f32 aw stores,
// pass B reversed, max-free softmax, wave-private Ps.
template <int CAUSAL>
__global__ __launch_bounds__(512, 4) void k_attn_fused(
    const u16* __restrict__ qh, const u16* __restrict__ kh,
    const u16* __restrict__ vtg, const float* __restrict__ pmask,
    float* __restrict__ aw, u16* __restrict__ ctx) {
  __shared__ u16 Kt[2][128 * 64];  // [buf][key][dh] swizzled, 32 KB
  __shared__ u16 Vs[64 * 128];     // [d][key]  swizzled, 16 KB
  __shared__ u16 Ps[128 * 128];    // [q][key]  swizzled, wave-private, 32 KB

  const int jb = blockIdx.x;
  const int lo = jb & 255;
  const int bh = lo & 127;
  const int sel = lo >> 7;
  const int bx = (jb >> 8) == 0 ? sel : 3 - sel;
  const int b = bh >> 3, h = bh & 7;
  const int brow = bx * 128;
  const int tid = threadIdx.x, lane = tid & 63, wid = tid >> 6;
  const int l15 = lane & 15, g4 = lane >> 4;
  const u16* Q = qh + (size_t)bh * NSQ * NDH;
  const u16* Kg = kh + (size_t)bh * NSE * NDH;
  const u16* Vg = vtg + (size_t)bh * NDH * NSE;
  float* awp = aw + (size_t)bh * NSQ * NSE;

  const int krow = wid * 8 + (lane >> 3);            // 0..63
  const int ksw = ((lane & 7) ^ (krow & 7)) * 8;     // K src swizzle
  const int vsw = (l15 ^ ((wid * 4 + g4) & 7)) * 8;  // V src swizzle

  bf16x8 qf[2];
#pragma unroll
  for (int kk = 0; kk < 2; ++kk)
    qf[kk] = *(const bf16x8*)(Q + (size_t)(brow + wid * 16 + l15) * NDH +
                              kk * 32 + g4 * 8);

  const int ntile = CAUSAL ? bx + 1 : 4;

  auto stage_k = [&](int kb, int buf) {
#pragma unroll
    for (int v = 0; v < 2; ++v)
      gl_lds16(Kg + (size_t)(kb + v * 64 + krow) * NDH + ksw,
               Kt[buf] + (v * 64 + wid * 8) * 64);
  };
  auto stage_v = [&](int kb) {
#pragma unroll
    for (int v = 0; v < 2; ++v) {
      const int d = v * 32 + wid * 4 + g4;
      gl_lds16(Vg + (size_t)d * NSE + kb + vsw, Vs + (v * 32 + wid * 4) * 128);
    }
  };
  auto computeS = [&](int kb, int buf, f32x4(&acc)[8]) {
    const u16* kt = Kt[buf];
#pragma unroll
    for (int kk = 0; kk < 2; ++kk) {
      bf16x8 kf[8];
#pragma unroll
      for (int n = 0; n < 8; ++n) {
        const int kr = n * 16 + l15;
        kf[n] = *(const bf16x8*)(kt + kr * 64 + ((kk * 32 + g4 * 8) ^ ((kr & 7) << 3)));
      }
#pragma unroll
      for (int n = 0; n < 8; ++n)
        acc[n] = __builtin_amdgcn_mfma_f32_16x16x32_bf16(qf[kk], kf[n], acc[n], 0, 0, 0);
    }
    if (!CAUSAL) {
      float pm[8];
#pragma unroll
      for (int n = 0; n < 8; ++n)
        pm[n] = pmask[b * NSE + kb + n * 16 + l15] * (-1e9f);
#pragma unroll
      for (int n = 0; n < 8; ++n)
#pragma unroll
        for (int j = 0; j < 4; ++j)
          acc[n][j] = fminf(acc[n][j] * 0.125f, 60.0f) + pm[n];
    } else {
#pragma unroll
      for (int n = 0; n < 8; ++n) {
        const int key = kb + n * 16 + l15;
#pragma unroll
        for (int j = 0; j < 4; ++j) {
          const int qrow = brow + wid * 16 + g4 * 4 + j;
          acc[n][j] = (key > qrow) ? -1e9f : fminf(acc[n][j] * 0.125f, 60.0f);
        }
      }
    }
  };

  // ---- pass A: row sums (max-free); K dbuf, 1 barrier/tile ----
  float l4[4] = {0.f, 0.f, 0.f, 0.f};
  stage_k(0, 0);
  __syncthreads();
  for (int t = 0; t < ntile; ++t) {
    const int cur = t & 1;
    if (t + 1 < ntile) stage_k((t + 1) * 128, cur ^ 1);  // ages under computeS
    f32x4 acc[8] = {};
    computeS(t * 128, cur, acc);
#pragma unroll
    for (int j = 0; j < 4; ++j) {
      float s = 0.f;
#pragma unroll
      for (int n = 0; n < 8; ++n) s += __expf(acc[n][j]);
#pragma unroll
      for (int o = 1; o < 16; o <<= 1) s += __shfl_xor(s, o, 64);
      l4[j] += s;
    }
    __syncthreads();  // drain prefetch; all waves done with Kt[cur]
  }
  float invl[4];
#pragma unroll
  for (int j = 0; j < 4; ++j) invl[j] = 1.0f / l4[j];

  // ---- pass B: reversed; first tile's K resident from pass A ----
  f32x4 apv[4] = {};
  for (int t = ntile - 1; t >= 0; --t) {
    const int kb = t * 128;
    const int cur = t & 1;
    if (t > 0) stage_k((t - 1) * 128, cur ^ 1);  // ages under computeS
    stage_v(kb);                                 // ages under computeS
    f32x4 acc[8] = {};
    computeS(kb, cur, acc);
    __syncthreads();  // drain V(t)+K(t-1); all waves done with Kt[cur]
#pragma unroll
    for (int n = 0; n < 8; ++n) {
      const int col = n * 16 + l15;
#pragma unroll
      for (int j = 0; j < 4; ++j) {
        const int rl = wid * 16 + g4 * 4 + j;
        const float p = __expf(acc[n][j]) * invl[j];
        awp[(size_t)(brow + rl) * NSE + kb + col] = p;
        Ps[rl * 128 + (col ^ ((rl & 7) << 3))] = f2b(p);
      }
    }
    // PV: reads only this wave's Ps rows -> no barrier needed before it
#pragma unroll
    for (int kk = 0; kk < 4; ++kk) {
      const int qr = wid * 16 + l15;
      bf16x8 pa =
          *(const bf16x8*)(Ps + qr * 128 + ((kk * 32 + g4 * 8) ^ ((qr & 7) << 3)));
      bf16x8 vb[4];
#pragma unroll
      for (int n = 0; n < 4; ++n) {
        const int d = n * 16 + l15;
        vb[n] = *(const bf16x8*)(Vs + d * 128 + ((kk * 32 + g4 * 8) ^ ((d & 7) << 3)));
      }
#pragma unroll
      for (int n = 0; n < 4; ++n)
        apv[n] = __builtin_amdgcn_mfma_f32_16x16x32_bf16(pa, vb[n], apv[n], 0, 0, 0);
    }
    __syncthreads();  // all waves done with Vs before next stage_v
  }

  if (CAUSAL) {
    const float4 z4 = make_float4(0.f, 0.f, 0.f, 0.f);
    for (int t = ntile; t < 4; ++t) {
      const int r = tid >> 2, c0 = t * 128 + (tid & 3) * 32;
      float4* p = (float4*)(awp + (size_t)(brow + r) * NSE + c0);
#pragma unroll
      for (int i = 0; i < 8; ++i) p[i] = z4;
    }
  }

#pragma unroll
  for (int n = 0; n < 4; ++n) {
    const int d = n * 16 + l15;
#pragma unroll
    for (int j = 0; j < 4; ++j) {
      const int r = brow + wid * 16 + g4 * 4 + j;
      ctx[((size_t)(b * NSQ + r)) * ND + h * NDH + d] = f2b(apv[n][j]);
    }
  }
}

// ---------------- residual + LayerNorm (one wave per 512-row) ------------------
template <int B_BF16, int OUT_F32>
__global__ __launch_bounds__(256) void k_res_ln(const u16* __restrict__ a,
                                                const void* __restrict__ bsrc,
                                                const float* __restrict__ g,
                                                const float* __restrict__ bet,
                                                void* __restrict__ outp) {
  const int row = blockIdx.x * 4 + (threadIdx.x >> 6);
  const int lane = threadIdx.x & 63;
  const size_t base = (size_t)row * 512 + lane * 8;
  float s[8];
  {
    uint4 av = *(const uint4*)(a + base);
    s[0] = b2f(av.x & 0xffffu); s[1] = b2f(av.x >> 16);
    s[2] = b2f(av.y & 0xffffu); s[3] = b2f(av.y >> 16);
    s[4] = b2f(av.z & 0xffffu); s[5] = b2f(av.z >> 16);
    s[6] = b2f(av.w & 0xffffu); s[7] = b2f(av.w >> 16);
  }
  if (B_BF16) {
    uint4 bv = *(const uint4*)((const u16*)bsrc + base);
    s[0] += b2f(bv.x & 0xffffu); s[1] += b2f(bv.x >> 16);
    s[2] += b2f(bv.y & 0xffffu); s[3] += b2f(bv.y >> 16);
    s[4] += b2f(bv.z & 0xffffu); s[5] += b2f(bv.z >> 16);
    s[6] += b2f(bv.w & 0xffffu); s[7] += b2f(bv.w >> 16);
  } else {
    const float* bp = (const float*)bsrc + base;
    float4 b0 = *(const float4*)bp, b1 = *(const float4*)(bp + 4);
    s[0] += b0.x; s[1] += b0.y; s[2] += b0.z; s[3] += b0.w;
    s[4] += b1.x; s[5] += b1.y; s[6] += b1.z; s[7] += b1.w;
  }
  float sum = 0.f;
#pragma unroll
  for (int i = 0; i < 8; ++i) sum += s[i];
#pragma unroll
  for (int o = 1; o < 64; o <<= 1) sum += __shfl_xor(sum, o, 64);
  const float mu = sum * (1.0f / 512.0f);
  float vs = 0.f;
#pragma unroll
  for (int i = 0; i < 8; ++i) {
    const float d = s[i] - mu;
    vs += d * d;
  }
#pragma unroll
  for (int o = 1; o < 64; o <<= 1) vs += __shfl_xor(vs, o, 64);
  const float rs = rsqrtf(vs * (1.0f / 512.0f) + 1e-6f);
  float y[8];
#pragma unroll
  for (int i = 0; i < 8; ++i) {
    const int c = lane * 8 + i;
    y[i] = (s[i] - mu) * rs * g[c] + bet[c];
  }
  if (OUT_F32) {
    float* op = (float*)outp + base;
    *(float4*)op = make_float4(y[0], y[1], y[2], y[3]);
    *(float4*)(op + 4) = make_float4(y[4], y[5], y[6], y[7]);
  } else {
    uint4 o;
    o.x = (uint32_t)f2b(y[0]) | ((uint32_t)f2b(y[1]) << 16);
    o.y = (uint32_t)f2b(y[2]) | ((uint32_t)f2b(y[3]) << 16);
    o.z = (uint32_t)f2b(y[4]) | ((uint32_t)f2b(y[5]) << 16);
    o.w = (uint32_t)f2b(y[6]) | ((uint32_t)f2b(y[7]) << 16);
    *(uint4*)((u16*)outp + base) = o;
  }
}

extern "C" void kernel_launch(void* const* d_in, const int* in_sizes, int n_in,
                              void* d_out, int out_size, void* d_ws, size_t ws_size,
                              hipStream_t stream) {
  (void)in_sizes; (void)n_in; (void)out_size; (void)ws_size;
  const float* x = (const float*)d_in[0];
  const float* enc_fc = (const float*)d_in[1];
  const float* enc_ff = (const float*)d_in[2];
  const float* pmask = (const float*)d_in[4];
  const float* w_m1[4] = {(const float*)d_in[5], (const float*)d_in[7],
                          (const float*)d_in[9], (const float*)d_in[11]};
  const float* b_m1[4] = {(const float*)d_in[6], (const float*)d_in[8],
                          (const float*)d_in[10], (const float*)d_in[12]};
  const float* w_m2[4] = {(const float*)d_in[13], (const float*)d_in[15],
                          (const float*)d_in[17], (const float*)d_in[19]};
  const float* b_m2[4] = {(const float*)d_in[14], (const float*)d_in[16],
                          (const float*)d_in[18], (const float*)d_in[20]};
  const float* ffn_w1 = (const float*)d_in[21];
  const float* ffn_b1 = (const float*)d_in[22];
  const float* ffn_w2 = (const float*)d_in[23];
  const float* ffn_b2 = (const float*)d_in[24];
  const float* ln_g[3] = {(const float*)d_in[25], (const float*)d_in[27],
                          (const float*)d_in[29]};
  const float* ln_b[3] = {(const float*)d_in[26], (const float*)d_in[28],
                          (const float*)d_in[30]};

  char* ws = (char*)d_ws;
  const size_t SZB = (size_t)8192 * 512 * 2;  // 8 MiB bf16 activation buffer
  u16* xb = (u16*)(ws + 0 * SZB);
  u16* fcb = (u16*)(ws + 1 * SZB);
  u16* ffb = (u16*)(ws + 2 * SZB);
  u16* qh = (u16*)(ws + 3 * SZB);
  u16* kh = (u16*)(ws + 4 * SZB);
  u16* vt = (u16*)(ws + 5 * SZB);
  u16* ctx = (u16*)(ws + 6 * SZB);
  u16* ao = (u16*)(ws + 7 * SZB);
  u16* out1 = (u16*)(ws + 8 * SZB);
  u16* out2 = (u16*)(ws + 9 * SZB);
  u16* ffv = (u16*)(ws + 10 * SZB);
  u16* ff1 = (u16*)(ws + 11 * SZB);  // 32 MiB
  u16* wts = (u16*)(ws + 11 * SZB + (size_t)8192 * 2048 * 2);
  u16 *wt_m1[4], *wt_m2[4];
  for (int i = 0; i < 4; ++i) {
    wt_m1[i] = wts + (size_t)i * 262144;
    wt_m2[i] = wts + (size_t)(4 + i) * 262144;
  }
  u16* w1t = wts + (size_t)8 * 262144;  // [2048,512]
  u16* w2t = w1t + (size_t)2048 * 512;  // [512,2048]

  float* out3 = (float*)d_out;
  float* aw1 = out3 + (size_t)NB * NSQ * ND;
  float* aw2 = aw1 + (size_t)NB * NH * NSQ * NSQ;

  // prep: single dispatch (casts + all weight transposes)
  Prep pr;
  pr.x = x; pr.fc = enc_fc; pr.ff = enc_ff;
  pr.xb = xb; pr.fcb = fcb; pr.ffb = ffb;
  for (int i = 0; i < 4; ++i) {
    pr.w8[i] = w_m1[i]; pr.o8[i] = wt_m1[i];
    pr.w8[4 + i] = w_m2[i]; pr.o8[4 + i] = wt_m2[i];
  }
  pr.w1 = ffn_w1; pr.w1t = w1t;
  pr.w2 = ffn_w2; pr.w2t = w2t;
  k_prep<<<10240, 256, 0, stream>>>(pr);

  // MHA1 (self, causal)
  QKV q1 = {{xb, xb, xb},
            {wt_m1[0], wt_m1[1], wt_m1[2]},
            {b_m1[0], b_m1[1], b_m1[2]},
            {qh, kh, vt}};
  k_gemm_qkv<<<dim3(64, 4, 3), 256, 0, stream>>>(q1);
  k_attn_fused<1><<<512, 512, 0, stream>>>(qh, kh, vt, nullptr, aw1, ctx);
  k_gemm<64, EPI_GELU><<<dim3(128, 4), 256, 0, stream>>>(ctx, wt_m1[3], b_m1[3], ao, 512, 512);
  k_res_ln<0, 0><<<2048, 256, 0, stream>>>(ao, x, ln_g[0], ln_b[0], out1);
  // MHA2 (cross, padding mask): q=out1, k=enc_fc, v=enc_ff
  QKV q2 = {{out1, fcb, ffb},
            {wt_m2[0], wt_m2[1], wt_m2[2]},
            {b_m2[0], b_m2[1], b_m2[2]},
            {qh, kh, vt}};
  k_gemm_qkv<<<dim3(64, 4, 3), 256, 0, stream>>>(q2);
  k_attn_fused<0><<<512, 512, 0, stream>>>(qh, kh, vt, pmask, aw2, ctx);
  k_gemm<64, EPI_GELU><<<dim3(128, 4), 256, 0, stream>>>(ctx, wt_m2[3], b_m2[3], ao, 512, 512);
  k_res_ln<1, 0><<<2048, 256, 0, stream>>>(ao, out1, ln_g[1], ln_b[1], out2);
  // FFN
  k_gemm<128, EPI_RELU><<<dim3(64, 16), 256, 0, stream>>>(out2, w1t, ffn_b1, ff1, 512, 2048);
  k_gemm<64, EPI_NONE><<<dim3(128, 4), 256, 0, stream>>>(ff1, w2t, ffn_b2, ffv, 2048, 512);
  k_res_ln<1, 1><<<2048, 256, 0, stream>>>(ffv, out2, ln_g[2], ln_b[2], (void*)d_out);
}

// Round 13
// 311.486 us; speedup vs baseline: 1.1636x; 1.1636x over previous
//
#include <hip/hip_runtime.h>
#include <stdint.h>
#include <math.h>

typedef unsigned short u16;
typedef __attribute__((ext_vector_type(8))) __bf16 bf16x8;
typedef __attribute__((ext_vector_type(4))) float f32x4;

#define NB 16
#define NSQ 512
#define NSE 512
#define ND 512
#define NH 8
#define NDH 64
#define NDFF 2048

__device__ __forceinline__ u16 f2b(float f) {
  uint32_t u = __float_as_uint(f);
  u = (u + 0x7FFFu + ((u >> 16) & 1u)) >> 16;
  return (u16)u;
}
__device__ __forceinline__ float b2f(uint32_t h) {
  return __uint_as_float(h << 16);
}

// async global->LDS, 16B per lane; LDS dest = wave-uniform base + lane*16
__device__ __forceinline__ void gl_lds16(const u16* g, u16* l) {
  __builtin_amdgcn_global_load_lds(
      (const __attribute__((address_space(1))) void*)g,
      (__attribute__((address_space(3))) void*)l, 16, 0, 0);
}

// ---------------- fused prep: 3 casts + 10 weight transposes, ONE dispatch ----
struct Prep {
  const float *x, *fc, *ff;
  u16 *xb, *fcb, *ffb;
  const float* w8[8];
  u16* o8[8];
  const float *w1, *w2;
  u16 *w1t, *w2t;
};

__device__ __forceinline__ void tr32(const float* __restrict__ W,
                                     u16* __restrict__ Wt, int K, int N, int bx,
                                     int by, float (*t)[33]) {
  const int tid = threadIdx.x, tx = tid & 31, ty = tid >> 5;
  const int n0 = bx * 32, k0 = by * 32;
#pragma unroll
  for (int i = 0; i < 32; i += 8)
    t[ty + i][tx] = W[(size_t)(k0 + ty + i) * N + n0 + tx];
  __syncthreads();
#pragma unroll
  for (int i = 0; i < 32; i += 8)
    Wt[(size_t)(n0 + ty + i) * K + k0 + tx] = f2b(t[tx][ty + i]);
}

__global__ void k_prep(Prep p) {
  __shared__ float t[32][33];
  const int blk = blockIdx.x;
  if (blk < 6144) {  // 3 activation casts, 8 elems/thread
    const int plane = blk >> 11;
    const float* src = plane == 0 ? p.x : (plane == 1 ? p.fc : p.ff);
    u16* dst = plane == 0 ? p.xb : (plane == 1 ? p.fcb : p.ffb);
    const int i = (blk & 2047) * 256 + threadIdx.x;
    const float4* q = (const float4*)(src + (size_t)i * 8);
    float4 v0 = q[0], v1 = q[1];
    uint4 o;
    o.x = (uint32_t)f2b(v0.x) | ((uint32_t)f2b(v0.y) << 16);
    o.y = (uint32_t)f2b(v0.z) | ((uint32_t)f2b(v0.w) << 16);
    o.z = (uint32_t)f2b(v1.x) | ((uint32_t)f2b(v1.y) << 16);
    o.w = (uint32_t)f2b(v1.z) | ((uint32_t)f2b(v1.w) << 16);
    *(uint4*)(dst + (size_t)i * 8) = o;
  } else if (blk < 8192) {  // 8 attention weights 512x512
    const int b2 = blk - 6144, z = b2 >> 8, bi = b2 & 255;
    tr32(p.w8[z], p.o8[z], 512, 512, bi & 15, bi >> 4, t);
  } else if (blk < 9216) {  // ffn_w1 [512,2048]
    const int b2 = blk - 8192;
    tr32(p.w1, p.w1t, 512, 2048, b2 & 63, b2 >> 6, t);
  } else {  // ffn_w2 [2048,512]
    const int b2 = blk - 9216;
    tr32(p.w2, p.w2t, 2048, 512, b2 & 15, b2 >> 4, t);
  }
}

// ---------------- GEMM core: m97 single-buffer structure (r11-proven) ---------
// SWAP=true computes the transposed tile via mfma(B_frag, A_frag) (= C^T):
// then l15 indexes A-rows (M) and g4*4+j indexes B-rows (N). Used by the
// V-projection so its [b,h,d,s] store is coalesced along s.
enum { EPI_GELU = 2, EPI_RELU = 3, EPI_NONE = 4 };

template <int BM, bool SWAP>
__device__ __forceinline__ void gemm_core(const u16* __restrict__ A,
                                          const u16* __restrict__ Bt, int K,
                                          int brow, int bcol, u16* As, u16* Bs,
                                          f32x4 (&acc)[BM / 32][4]) {
  const int tid = threadIdx.x, lane = tid & 63, wid = tid >> 6;
  const int wr = wid >> 1, wc = wid & 1;
  const int l15 = lane & 15, g4 = lane >> 4;
  const int sc8 = (lane & 7) * 8;
  const int srow = wid * 8 + (lane >> 3);
  const int nt = K >> 6;
  for (int t = 0; t < nt; ++t) {
    const int k0 = t << 6;
    if (t) __syncthreads();
#pragma unroll
    for (int v = 0; v < BM / 32; ++v)
      gl_lds16(A + (size_t)(brow + v * 32 + srow) * K + k0 + sc8,
               As + (v * 32 + wid * 8) * 64);
#pragma unroll
    for (int v = 0; v < 4; ++v)
      gl_lds16(Bt + (size_t)(bcol + v * 32 + srow) * K + k0 + sc8,
               Bs + (v * 32 + wid * 8) * 64);
    __syncthreads();
#pragma unroll
    for (int kk = 0; kk < 2; ++kk) {
      bf16x8 af[BM / 32], bfr[4];
#pragma unroll
      for (int m = 0; m < BM / 32; ++m)
        af[m] = *(const bf16x8*)(As + (wr * (BM / 2) + m * 16 + l15) * 64 +
                                 kk * 32 + g4 * 8);
#pragma unroll
      for (int n = 0; n < 4; ++n)
        bfr[n] = *(const bf16x8*)(Bs + (wc * 64 + n * 16 + l15) * 64 +
                                  kk * 32 + g4 * 8);
#pragma unroll
      for (int m = 0; m < BM / 32; ++m)
#pragma unroll
        for (int n = 0; n < 4; ++n)
          acc[m][n] =
              SWAP ? __builtin_amdgcn_mfma_f32_16x16x32_bf16(bfr[n], af[m],
                                                             acc[m][n], 0, 0, 0)
                   : __builtin_amdgcn_mfma_f32_16x16x32_bf16(af[m], bfr[n],
                                                             acc[m][n], 0, 0, 0);
    }
  }
}

template <int BM, int EPI>
__global__ __launch_bounds__(256, 3) void k_gemm(
    const u16* __restrict__ A, const u16* __restrict__ Bt,
    const float* __restrict__ bias, u16* __restrict__ out, int K, int N) {
  __shared__ u16 As[BM * 64];
  __shared__ u16 Bs[128 * 64];
  f32x4 acc[BM / 32][4] = {};
  const int brow = blockIdx.x * BM, bcol = blockIdx.y * 128;
  gemm_core<BM, false>(A, Bt, K, brow, bcol, As, Bs, acc);
  const int lane = threadIdx.x & 63, wid = threadIdx.x >> 6;
  const int wr = wid >> 1, wc = wid & 1, l15 = lane & 15, g4 = lane >> 4;
#pragma unroll
  for (int m = 0; m < BM / 32; ++m) {
    const int r0 = brow + wr * (BM / 2) + m * 16 + g4 * 4;
#pragma unroll
    for (int n = 0; n < 4; ++n) {
      const int col = bcol + wc * 64 + n * 16 + l15;
      const float bv = bias[col];
#pragma unroll
      for (int j = 0; j < 4; ++j) {
        float vv = acc[m][n][j] + bv;
        if (EPI == EPI_GELU) vv = 0.5f * vv * (1.0f + erff(vv * 0.70710678118654752f));
        if (EPI == EPI_RELU) vv = fmaxf(vv, 0.0f);
        out[(size_t)(r0 + j) * N + col] = f2b(vv);
      }
    }
  }
}

// fused Q/K/V projection: blockIdx.z picks weight/output.
// z<2: normal tile, out [b,h,s,d]. z==2: SWAPPED tile (C^T in registers),
// out [b,h,d,s] with s lane-varying -> coalesced stores.
struct QKV {
  const u16* A[3];
  const u16* Bt[3];
  const float* bias[3];
  u16* out[3];
};
__global__ __launch_bounds__(256, 3) void k_gemm_qkv(QKV p) {
  const int z = blockIdx.z;
  __shared__ u16 As[128 * 64];
  __shared__ u16 Bs[128 * 64];
  f32x4 acc[4][4] = {};
  const int brow = blockIdx.x * 128, bcol = blockIdx.y * 128;
  const int lane = threadIdx.x & 63, wid = threadIdx.x >> 6;
  const int wr = wid >> 1, wc = wid & 1, l15 = lane & 15, g4 = lane >> 4;
  const float* bias = p.bias[z];
  u16* out = p.out[z];
  if (z < 2) {
    gemm_core<128, false>(p.A[z], p.Bt[z], 512, brow, bcol, As, Bs, acc);
#pragma unroll
    for (int m = 0; m < 4; ++m) {
      const int r0 = brow + wr * 64 + m * 16 + g4 * 4;
#pragma unroll
      for (int n = 0; n < 4; ++n) {
        const int col = bcol + wc * 64 + n * 16 + l15;
        const float bv = bias[col];
        const int h = col >> 6, d = col & 63;
#pragma unroll
        for (int j = 0; j < 4; ++j) {
          const int r = r0 + j, b = r >> 9, s = r & 511;
          out[((size_t)(b * NH + h) * NSQ + s) * NDH + d] = f2b(acc[m][n][j] + bv);
        }
      }
    }
  } else {
    gemm_core<128, true>(p.A[z], p.Bt[z], 512, brow, bcol, As, Bs, acc);
    // swapped C^T mapping: l15 -> A-row (b,s); g4*4+j -> B-row (h,d)
    const int b = brow >> 9;  // 128 | 512 -> uniform per block
#pragma unroll
    for (int m = 0; m < 4; ++m) {
      const int s = (brow & 511) + wr * 64 + m * 16 + l15;
#pragma unroll
      for (int n = 0; n < 4; ++n) {
#pragma unroll
        for (int j = 0; j < 4; ++j) {
          const int col = bcol + wc * 64 + n * 16 + g4 * 4 + j;
          const int h = col >> 6, d = col & 63;
          out[((size_t)(b * NH + h) * NDH + d) * NSE + s] =
              f2b(acc[m][n][j] + bias[col]);
        }
      }
    }
  }
}

// ---------------- fused attention: logits + softmax + PV ----------------------
// r11-proven version, unchanged: K double-buffer (1 barrier/tile pass A;
// prefetch ages under computeS), balanced causal remap, normal f32 aw stores,
// pass B reversed, max-free softmax, wave-private Ps.
template <int CAUSAL>
__global__ __launch_bounds__(512, 4) void k_attn_fused(
    const u16* __restrict__ qh, const u16* __restrict__ kh,
    const u16* __restrict__ vtg, const float* __restrict__ pmask,
    float* __restrict__ aw, u16* __restrict__ ctx) {
  __shared__ u16 Kt[2][128 * 64];  // [buf][key][dh] swizzled, 32 KB
  __shared__ u16 Vs[64 * 128];     // [d][key]  swizzled, 16 KB
  __shared__ u16 Ps[128 * 128];    // [q][key]  swizzled, wave-private, 32 KB

  const int jb = blockIdx.x;
  const int lo = jb & 255;
  const int bh = lo & 127;
  const int sel = lo >> 7;
  const int bx = (jb >> 8) == 0 ? sel : 3 - sel;
  const int b = bh >> 3, h = bh & 7;
  const int brow = bx * 128;
  const int tid = threadIdx.x, lane = tid & 63, wid = tid >> 6;
  const int l15 = lane & 15, g4 = lane >> 4;
  const u16* Q = qh + (size_t)bh * NSQ * NDH;
  const u16* Kg = kh + (size_t)bh * NSE * NDH;
  const u16* Vg = vtg + (size_t)bh * NDH * NSE;
  float* awp = aw + (size_t)bh * NSQ * NSE;

  const int krow = wid * 8 + (lane >> 3);            // 0..63
  const int ksw = ((lane & 7) ^ (krow & 7)) * 8;     // K src swizzle
  const int vsw = (l15 ^ ((wid * 4 + g4) & 7)) * 8;  // V src swizzle

  bf16x8 qf[2];
#pragma unroll
  for (int kk = 0; kk < 2; ++kk)
    qf[kk] = *(const bf16x8*)(Q + (size_t)(brow + wid * 16 + l15) * NDH +
                              kk * 32 + g4 * 8);

  const int ntile = CAUSAL ? bx + 1 : 4;

  auto stage_k = [&](int kb, int buf) {
#pragma unroll
    for (int v = 0; v < 2; ++v)
      gl_lds16(Kg + (size_t)(kb + v * 64 + krow) * NDH + ksw,
               Kt[buf] + (v * 64 + wid * 8) * 64);
  };
  auto stage_v = [&](int kb) {
#pragma unroll
    for (int v = 0; v < 2; ++v) {
      const int d = v * 32 + wid * 4 + g4;
      gl_lds16(Vg + (size_t)d * NSE + kb + vsw, Vs + (v * 32 + wid * 4) * 128);
    }
  };
  auto computeS = [&](int kb, int buf, f32x4(&acc)[8]) {
    const u16* kt = Kt[buf];
#pragma unroll
    for (int kk = 0; kk < 2; ++kk) {
      bf16x8 kf[8];
#pragma unroll
      for (int n = 0; n < 8; ++n) {
        const int kr = n * 16 + l15;
        kf[n] = *(const bf16x8*)(kt + kr * 64 + ((kk * 32 + g4 * 8) ^ ((kr & 7) << 3)));
      }
#pragma unroll
      for (int n = 0; n < 8; ++n)
        acc[n] = __builtin_amdgcn_mfma_f32_16x16x32_bf16(qf[kk], kf[n], acc[n], 0, 0, 0);
    }
    if (!CAUSAL) {
      float pm[8];
#pragma unroll
      for (int n = 0; n < 8; ++n)
        pm[n] = pmask[b * NSE + kb + n * 16 + l15] * (-1e9f);
#pragma unroll
      for (int n = 0; n < 8; ++n)
#pragma unroll
        for (int j = 0; j < 4; ++j)
          acc[n][j] = fminf(acc[n][j] * 0.125f, 60.0f) + pm[n];
    } else {
#pragma unroll
      for (int n = 0; n < 8; ++n) {
        const int key = kb + n * 16 + l15;
#pragma unroll
        for (int j = 0; j < 4; ++j) {
          const int qrow = brow + wid * 16 + g4 * 4 + j;
          acc[n][j] = (key > qrow) ? -1e9f : fminf(acc[n][j] * 0.125f, 60.0f);
        }
      }
    }
  };

  // ---- pass A: row sums (max-free); K dbuf, 1 barrier/tile ----
  float l4[4] = {0.f, 0.f, 0.f, 0.f};
  stage_k(0, 0);
  __syncthreads();
  for (int t = 0; t < ntile; ++t) {
    const int cur = t & 1;
    if (t + 1 < ntile) stage_k((t + 1) * 128, cur ^ 1);  // ages under computeS
    f32x4 acc[8] = {};
    computeS(t * 128, cur, acc);
#pragma unroll
    for (int j = 0; j < 4; ++j) {
      float s = 0.f;
#pragma unroll
      for (int n = 0; n < 8; ++n) s += __expf(acc[n][j]);
#pragma unroll
      for (int o = 1; o < 16; o <<= 1) s += __shfl_xor(s, o, 64);
      l4[j] += s;
    }
    __syncthreads();  // drain prefetch; all waves done with Kt[cur]
  }
  float invl[4];
#pragma unroll
  for (int j = 0; j < 4; ++j) invl[j] = 1.0f / l4[j];

  // ---- pass B: reversed; first tile's K resident from pass A ----
  f32x4 apv[4] = {};
  for (int t = ntile - 1; t >= 0; --t) {
    const int kb = t * 128;
    const int cur = t & 1;
    if (t > 0) stage_k((t - 1) * 128, cur ^ 1);  // ages under computeS
    stage_v(kb);                                 // ages under computeS
    f32x4 acc[8] = {};
    computeS(kb, cur, acc);
    __syncthreads();  // drain V(t)+K(t-1); all waves done with Kt[cur]
#pragma unroll
    for (int n = 0; n < 8; ++n) {
      const int col = n * 16 + l15;
#pragma unroll
      for (int j = 0; j < 4; ++j) {
        const int rl = wid * 16 + g4 * 4 + j;
        const float p = __expf(acc[n][j]) * invl[j];
        awp[(size_t)(brow + rl) * NSE + kb + col] = p;
        Ps[rl * 128 + (col ^ ((rl & 7) << 3))] = f2b(p);
      }
    }
    // PV: reads only this wave's Ps rows -> no barrier needed before it
#pragma unroll
    for (int kk = 0; kk < 4; ++kk) {
      const int qr = wid * 16 + l15;
      bf16x8 pa =
          *(const bf16x8*)(Ps + qr * 128 + ((kk * 32 + g4 * 8) ^ ((qr & 7) << 3)));
      bf16x8 vb[4];
#pragma unroll
      for (int n = 0; n < 4; ++n) {
        const int d = n * 16 + l15;
        vb[n] = *(const bf16x8*)(Vs + d * 128 + ((kk * 32 + g4 * 8) ^ ((d & 7) << 3)));
      }
#pragma unroll
      for (int n = 0; n < 4; ++n)
        apv[n] = __builtin_amdgcn_mfma_f32_16x16x32_bf16(pa, vb[n], apv[n], 0, 0, 0);
    }
    __syncthreads();  // all waves done with Vs before next stage_v
  }

  if (CAUSAL) {
    const float4 z4 = make_float4(0.f, 0.f, 0.f, 0.f);
    for (int t = ntile; t < 4; ++t) {
      const int r = tid >> 2, c0 = t * 128 + (tid & 3) * 32;
      float4* p = (float4*)(awp + (size_t)(brow + r) * NSE + c0);
#pragma unroll
      for (int i = 0; i < 8; ++i) p[i] = z4;
    }
  }

#pragma unroll
  for (int n = 0; n < 4; ++n) {
    const int d = n * 16 + l15;
#pragma unroll
    for (int j = 0; j < 4; ++j) {
      const int r = brow + wid * 16 + g4 * 4 + j;
      ctx[((size_t)(b * NSQ + r)) * ND + h * NDH + d] = f2b(apv[n][j]);
    }
  }
}

// ---------------- residual + LayerNorm (one wave per 512-row) ------------------
template <int B_BF16, int OUT_F32>
__global__ __launch_bounds__(256) void k_res_ln(const u16* __restrict__ a,
                                                const void* __restrict__ bsrc,
                                                const float* __restrict__ g,
                                                const float* __restrict__ bet,
                                                void* __restrict__ outp) {
  const int row = blockIdx.x * 4 + (threadIdx.x >> 6);
  const int lane = threadIdx.x & 63;
  const size_t base = (size_t)row * 512 + lane * 8;
  float s[8];
  {
    uint4 av = *(const uint4*)(a + base);
    s[0] = b2f(av.x & 0xffffu); s[1] = b2f(av.x >> 16);
    s[2] = b2f(av.y & 0xffffu); s[3] = b2f(av.y >> 16);
    s[4] = b2f(av.z & 0xffffu); s[5] = b2f(av.z >> 16);
    s[6] = b2f(av.w & 0xffffu); s[7] = b2f(av.w >> 16);
  }
  if (B_BF16) {
    uint4 bv = *(const uint4*)((const u16*)bsrc + base);
    s[0] += b2f(bv.x & 0xffffu); s[1] += b2f(bv.x >> 16);
    s[2] += b2f(bv.y & 0xffffu); s[3] += b2f(bv.y >> 16);
    s[4] += b2f(bv.z & 0xffffu); s[5] += b2f(bv.z >> 16);
    s[6] += b2f(bv.w & 0xffffu); s[7] += b2f(bv.w >> 16);
  } else {
    const float* bp = (const float*)bsrc + base;
    float4 b0 = *(const float4*)bp, b1 = *(const float4*)(bp + 4);
    s[0] += b0.x; s[1] += b0.y; s[2] += b0.z; s[3] += b0.w;
    s[4] += b1.x; s[5] += b1.y; s[6] += b1.z; s[7] += b1.w;
  }
  float sum = 0.f;
#pragma unroll
  for (int i = 0; i < 8; ++i) sum += s[i];
#pragma unroll
  for (int o = 1; o < 64; o <<= 1) sum += __shfl_xor(sum, o, 64);
  const float mu = sum * (1.0f / 512.0f);
  float vs = 0.f;
#pragma unroll
  for (int i = 0; i < 8; ++i) {
    const float d = s[i] - mu;
    vs += d * d;
  }
#pragma unroll
  for (int o = 1; o < 64; o <<= 1) vs += __shfl_xor(vs, o, 64);
  const float rs = rsqrtf(vs * (1.0f / 512.0f) + 1e-6f);
  float y[8];
#pragma unroll
  for (int i = 0; i < 8; ++i) {
    const int c = lane * 8 + i;
    y[i] = (s[i] - mu) * rs * g[c] + bet[c];
  }
  if (OUT_F32) {
    float* op = (float*)outp + base;
    *(float4*)op = make_float4(y[0], y[1], y[2], y[3]);
    *(float4*)(op + 4) = make_float4(y[4], y[5], y[6], y[7]);
  } else {
    uint4 o;
    o.x = (uint32_t)f2b(y[0]) | ((uint32_t)f2b(y[1]) << 16);
    o.y = (uint32_t)f2b(y[2]) | ((uint32_t)f2b(y[3]) << 16);
    o.z = (uint32_t)f2b(y[4]) | ((uint32_t)f2b(y[5]) << 16);
    o.w = (uint32_t)f2b(y[6]) | ((uint32_t)f2b(y[7]) << 16);
    *(uint4*)((u16*)outp + base) = o;
  }
}

extern "C" void kernel_launch(void* const* d_in, const int* in_sizes, int n_in,
                              void* d_out, int out_size, void* d_ws, size_t ws_size,
                              hipStream_t stream) {
  (void)in_sizes; (void)n_in; (void)out_size; (void)ws_size;
  const float* x = (const float*)d_in[0];
  const float* enc_fc = (const float*)d_in[1];
  const float* enc_ff = (const float*)d_in[2];
  const float* pmask = (const float*)d_in[4];
  const float* w_m1[4] = {(const float*)d_in[5], (const float*)d_in[7],
                          (const float*)d_in[9], (const float*)d_in[11]};
  const float* b_m1[4] = {(const float*)d_in[6], (const float*)d_in[8],
                          (const float*)d_in[10], (const float*)d_in[12]};
  const float* w_m2[4] = {(const float*)d_in[13], (const float*)d_in[15],
                          (const float*)d_in[17], (const float*)d_in[19]};
  const float* b_m2[4] = {(const float*)d_in[14], (const float*)d_in[16],
                          (const float*)d_in[18], (const float*)d_in[20]};
  const float* ffn_w1 = (const float*)d_in[21];
  const float* ffn_b1 = (const float*)d_in[22];
  const float* ffn_w2 = (const float*)d_in[23];
  const float* ffn_b2 = (const float*)d_in[24];
  const float* ln_g[3] = {(const float*)d_in[25], (const float*)d_in[27],
                          (const float*)d_in[29]};
  const float* ln_b[3] = {(const float*)d_in[26], (const float*)d_in[28],
                          (const float*)d_in[30]};

  char* ws = (char*)d_ws;
  const size_t SZB = (size_t)8192 * 512 * 2;  // 8 MiB bf16 activation buffer
  u16* xb = (u16*)(ws + 0 * SZB);
  u16* fcb = (u16*)(ws + 1 * SZB);
  u16* ffb = (u16*)(ws + 2 * SZB);
  u16* qh = (u16*)(ws + 3 * SZB);
  u16* kh = (u16*)(ws + 4 * SZB);
  u16* vt = (u16*)(ws + 5 * SZB);
  u16* ctx = (u16*)(ws + 6 * SZB);
  u16* ao = (u16*)(ws + 7 * SZB);
  u16* out1 = (u16*)(ws + 8 * SZB);
  u16* out2 = (u16*)(ws + 9 * SZB);
  u16* ffv = (u16*)(ws + 10 * SZB);
  u16* ff1 = (u16*)(ws + 11 * SZB);  // 32 MiB
  u16* wts = (u16*)(ws + 11 * SZB + (size_t)8192 * 2048 * 2);
  u16 *wt_m1[4], *wt_m2[4];
  for (int i = 0; i < 4; ++i) {
    wt_m1[i] = wts + (size_t)i * 262144;
    wt_m2[i] = wts + (size_t)(4 + i) * 262144;
  }
  u16* w1t = wts + (size_t)8 * 262144;  // [2048,512]
  u16* w2t = w1t + (size_t)2048 * 512;  // [512,2048]

  float* out3 = (float*)d_out;
  float* aw1 = out3 + (size_t)NB * NSQ * ND;
  float* aw2 = aw1 + (size_t)NB * NH * NSQ * NSQ;

  // prep: single dispatch (casts + all weight transposes)
  Prep pr;
  pr.x = x; pr.fc = enc_fc; pr.ff = enc_ff;
  pr.xb = xb; pr.fcb = fcb; pr.ffb = ffb;
  for (int i = 0; i < 4; ++i) {
    pr.w8[i] = w_m1[i]; pr.o8[i] = wt_m1[i];
    pr.w8[4 + i] = w_m2[i]; pr.o8[4 + i] = wt_m2[i];
  }
  pr.w1 = ffn_w1; pr.w1t = w1t;
  pr.w2 = ffn_w2; pr.w2t = w2t;
  k_prep<<<10240, 256, 0, stream>>>(pr);

  // MHA1 (self, causal)
  QKV q1 = {{xb, xb, xb},
            {wt_m1[0], wt_m1[1], wt_m1[2]},
            {b_m1[0], b_m1[1], b_m1[2]},
            {qh, kh, vt}};
  k_gemm_qkv<<<dim3(64, 4, 3), 256, 0, stream>>>(q1);
  k_attn_fused<1><<<512, 512, 0, stream>>>(qh, kh, vt, nullptr, aw1, ctx);
  k_gemm<64, EPI_GELU><<<dim3(128, 4), 256, 0, stream>>>(ctx, wt_m1[3], b_m1[3], ao, 512, 512);
  k_res_ln<0, 0><<<2048, 256, 0, stream>>>(ao, x, ln_g[0], ln_b[0], out1);
  // MHA2 (cross, padding mask): q=out1, k=enc_fc, v=enc_ff
  QKV q2 = {{out1, fcb, ffb},
            {wt_m2[0], wt_m2[1], wt_m2[2]},
            {b_m2[0], b_m2[1], b_m2[2]},
            {qh, kh, vt}};
  k_gemm_qkv<<<dim3(64, 4, 3), 256, 0, stream>>>(q2);
  k_attn_fused<0><<<512, 512, 0, stream>>>(qh, kh, vt, pmask, aw2, ctx);
  k_gemm<64, EPI_GELU><<<dim3(128, 4), 256, 0, stream>>>(ctx, wt_m2[3], b_m2[3], ao, 512, 512);
  k_res_ln<1, 0><<<2048, 256, 0, stream>>>(ao, out1, ln_g[1], ln_b[1], out2);
  // FFN
  k_gemm<128, EPI_RELU><<<dim3(64, 16), 256, 0, stream>>>(out2, w1t, ffn_b1, ff1, 512, 2048);
  k_gemm<64, EPI_NONE><<<dim3(128, 4), 256, 0, stream>>>(ff1, w2t, ffn_b2, ffv, 2048, 512);
  k_res_ln<1, 1><<<2048, 256, 0, stream>>>(ffv, out2, ln_g[2], ln_b[2], (void*)d_out);
}

// Round 14
// 299.581 us; speedup vs baseline: 1.2098x; 1.0397x over previous
//
#include <hip/hip_runtime.h>
#include <stdint.h>
#include <math.h>

typedef unsigned short u16;
typedef __attribute__((ext_vector_type(8))) __bf16 bf16x8;
typedef __attribute__((ext_vector_type(4))) float f32x4;

#define NB 16
#define NSQ 512
#define NSE 512
#define ND 512
#define NH 8
#define NDH 64
#define NDFF 2048

__device__ __forceinline__ u16 f2b(float f) {
  uint32_t u = __float_as_uint(f);
  u = (u + 0x7FFFu + ((u >> 16) & 1u)) >> 16;
  return (u16)u;
}
__device__ __forceinline__ float b2f(uint32_t h) {
  return __uint_as_float(h << 16);
}

// async global->LDS, 16B per lane; LDS dest = wave-uniform base + lane*16
__device__ __forceinline__ void gl_lds16(const u16* g, u16* l) {
  __builtin_amdgcn_global_load_lds(
      (const __attribute__((address_space(1))) void*)g,
      (__attribute__((address_space(3))) void*)l, 16, 0, 0);
}

// ---------------- fused prep: 3 casts + 10 weight transposes, ONE dispatch ----
struct Prep {
  const float *x, *fc, *ff;
  u16 *xb, *fcb, *ffb;
  const float* w8[8];
  u16* o8[8];
  const float *w1, *w2;
  u16 *w1t, *w2t;
};

__device__ __forceinline__ void tr32(const float* __restrict__ W,
                                     u16* __restrict__ Wt, int K, int N, int bx,
                                     int by, float (*t)[33]) {
  const int tid = threadIdx.x, tx = tid & 31, ty = tid >> 5;
  const int n0 = bx * 32, k0 = by * 32;
#pragma unroll
  for (int i = 0; i < 32; i += 8)
    t[ty + i][tx] = W[(size_t)(k0 + ty + i) * N + n0 + tx];
  __syncthreads();
#pragma unroll
  for (int i = 0; i < 32; i += 8)
    Wt[(size_t)(n0 + ty + i) * K + k0 + tx] = f2b(t[tx][ty + i]);
}

__global__ void k_prep(Prep p) {
  __shared__ float t[32][33];
  const int blk = blockIdx.x;
  if (blk < 6144) {  // 3 activation casts, 8 elems/thread
    const int plane = blk >> 11;
    const float* src = plane == 0 ? p.x : (plane == 1 ? p.fc : p.ff);
    u16* dst = plane == 0 ? p.xb : (plane == 1 ? p.fcb : p.ffb);
    const int i = (blk & 2047) * 256 + threadIdx.x;
    const float4* q = (const float4*)(src + (size_t)i * 8);
    float4 v0 = q[0], v1 = q[1];
    uint4 o;
    o.x = (uint32_t)f2b(v0.x) | ((uint32_t)f2b(v0.y) << 16);
    o.y = (uint32_t)f2b(v0.z) | ((uint32_t)f2b(v0.w) << 16);
    o.z = (uint32_t)f2b(v1.x) | ((uint32_t)f2b(v1.y) << 16);
    o.w = (uint32_t)f2b(v1.z) | ((uint32_t)f2b(v1.w) << 16);
    *(uint4*)(dst + (size_t)i * 8) = o;
  } else if (blk < 8192) {  // 8 attention weights 512x512
    const int b2 = blk - 6144, z = b2 >> 8, bi = b2 & 255;
    tr32(p.w8[z], p.o8[z], 512, 512, bi & 15, bi >> 4, t);
  } else if (blk < 9216) {  // ffn_w1 [512,2048]
    const int b2 = blk - 8192;
    tr32(p.w1, p.w1t, 512, 2048, b2 & 63, b2 >> 6, t);
  } else {  // ffn_w2 [2048,512]
    const int b2 = blk - 9216;
    tr32(p.w2, p.w2t, 2048, 512, b2 & 15, b2 >> 4, t);
  }
}

// ---------------- GEMM core: m97 single-buffer structure (r13-proven) ---------
// SWAP=true computes the transposed tile via mfma(B_frag, A_frag) (= C^T):
// then l15 indexes A-rows (M) and g4*4+j indexes B-rows (N). Used by the
// V-projection so its [b,h,d,s] store is coalesced along s.
enum { EPI_GELU = 2, EPI_RELU = 3, EPI_NONE = 4 };

template <int BM, bool SWAP>
__device__ __forceinline__ void gemm_core(const u16* __restrict__ A,
                                          const u16* __restrict__ Bt, int K,
                                          int brow, int bcol, u16* As, u16* Bs,
                                          f32x4 (&acc)[BM / 32][4]) {
  const int tid = threadIdx.x, lane = tid & 63, wid = tid >> 6;
  const int wr = wid >> 1, wc = wid & 1;
  const int l15 = lane & 15, g4 = lane >> 4;
  const int sc8 = (lane & 7) * 8;
  const int srow = wid * 8 + (lane >> 3);
  const int nt = K >> 6;
  for (int t = 0; t < nt; ++t) {
    const int k0 = t << 6;
    if (t) __syncthreads();
#pragma unroll
    for (int v = 0; v < BM / 32; ++v)
      gl_lds16(A + (size_t)(brow + v * 32 + srow) * K + k0 + sc8,
               As + (v * 32 + wid * 8) * 64);
#pragma unroll
    for (int v = 0; v < 4; ++v)
      gl_lds16(Bt + (size_t)(bcol + v * 32 + srow) * K + k0 + sc8,
               Bs + (v * 32 + wid * 8) * 64);
    __syncthreads();
#pragma unroll
    for (int kk = 0; kk < 2; ++kk) {
      bf16x8 af[BM / 32], bfr[4];
#pragma unroll
      for (int m = 0; m < BM / 32; ++m)
        af[m] = *(const bf16x8*)(As + (wr * (BM / 2) + m * 16 + l15) * 64 +
                                 kk * 32 + g4 * 8);
#pragma unroll
      for (int n = 0; n < 4; ++n)
        bfr[n] = *(const bf16x8*)(Bs + (wc * 64 + n * 16 + l15) * 64 +
                                  kk * 32 + g4 * 8);
#pragma unroll
      for (int m = 0; m < BM / 32; ++m)
#pragma unroll
        for (int n = 0; n < 4; ++n)
          acc[m][n] =
              SWAP ? __builtin_amdgcn_mfma_f32_16x16x32_bf16(bfr[n], af[m],
                                                             acc[m][n], 0, 0, 0)
                   : __builtin_amdgcn_mfma_f32_16x16x32_bf16(af[m], bfr[n],
                                                             acc[m][n], 0, 0, 0);
    }
  }
}

template <int BM, int EPI>
__global__ __launch_bounds__(256, 3) void k_gemm(
    const u16* __restrict__ A, const u16* __restrict__ Bt,
    const float* __restrict__ bias, u16* __restrict__ out, int K, int N) {
  __shared__ u16 As[BM * 64];
  __shared__ u16 Bs[128 * 64];
  f32x4 acc[BM / 32][4] = {};
  const int brow = blockIdx.x * BM, bcol = blockIdx.y * 128;
  gemm_core<BM, false>(A, Bt, K, brow, bcol, As, Bs, acc);
  const int lane = threadIdx.x & 63, wid = threadIdx.x >> 6;
  const int wr = wid >> 1, wc = wid & 1, l15 = lane & 15, g4 = lane >> 4;
#pragma unroll
  for (int m = 0; m < BM / 32; ++m) {
    const int r0 = brow + wr * (BM / 2) + m * 16 + g4 * 4;
#pragma unroll
    for (int n = 0; n < 4; ++n) {
      const int col = bcol + wc * 64 + n * 16 + l15;
      const float bv = bias[col];
#pragma unroll
      for (int j = 0; j < 4; ++j) {
        float vv = acc[m][n][j] + bv;
        if (EPI == EPI_GELU) vv = 0.5f * vv * (1.0f + erff(vv * 0.70710678118654752f));
        if (EPI == EPI_RELU) vv = fmaxf(vv, 0.0f);
        out[(size_t)(r0 + j) * N + col] = f2b(vv);
      }
    }
  }
}

// fused Q/K/V projection: blockIdx.z picks weight/output.
// z<2: normal tile, out [b,h,s,d]. z==2: SWAPPED tile (C^T in registers),
// out [b,h,d,s] with s lane-varying -> coalesced stores.
struct QKV {
  const u16* A[3];
  const u16* Bt[3];
  const float* bias[3];
  u16* out[3];
};
__global__ __launch_bounds__(256, 3) void k_gemm_qkv(QKV p) {
  const int z = blockIdx.z;
  __shared__ u16 As[128 * 64];
  __shared__ u16 Bs[128 * 64];
  f32x4 acc[4][4] = {};
  const int brow = blockIdx.x * 128, bcol = blockIdx.y * 128;
  const int lane = threadIdx.x & 63, wid = threadIdx.x >> 6;
  const int wr = wid >> 1, wc = wid & 1, l15 = lane & 15, g4 = lane >> 4;
  const float* bias = p.bias[z];
  u16* out = p.out[z];
  if (z < 2) {
    gemm_core<128, false>(p.A[z], p.Bt[z], 512, brow, bcol, As, Bs, acc);
#pragma unroll
    for (int m = 0; m < 4; ++m) {
      const int r0 = brow + wr * 64 + m * 16 + g4 * 4;
#pragma unroll
      for (int n = 0; n < 4; ++n) {
        const int col = bcol + wc * 64 + n * 16 + l15;
        const float bv = bias[col];
        const int h = col >> 6, d = col & 63;
#pragma unroll
        for (int j = 0; j < 4; ++j) {
          const int r = r0 + j, b = r >> 9, s = r & 511;
          out[((size_t)(b * NH + h) * NSQ + s) * NDH + d] = f2b(acc[m][n][j] + bv);
        }
      }
    }
  } else {
    gemm_core<128, true>(p.A[z], p.Bt[z], 512, brow, bcol, As, Bs, acc);
    // swapped C^T mapping: l15 -> A-row (b,s); g4*4+j -> B-row (h,d)
    const int b = brow >> 9;  // 128 | 512 -> uniform per block
#pragma unroll
    for (int m = 0; m < 4; ++m) {
      const int s = (brow & 511) + wr * 64 + m * 16 + l15;
#pragma unroll
      for (int n = 0; n < 4; ++n) {
#pragma unroll
        for (int j = 0; j < 4; ++j) {
          const int col = bcol + wc * 64 + n * 16 + g4 * 4 + j;
          const int h = col >> 6, d = col & 63;
          out[((size_t)(b * NH + h) * NDH + d) * NSE + s] =
              f2b(acc[m][n][j] + bias[col]);
        }
      }
    }
  }
}

// ---------------- fused attention: logits + softmax + PV ----------------------
// r13 base + pass-A last-tile P stash: Ps holds UNNORMALIZED exp'd P
// everywhere (apv scaled by invl once in the ctx epilogue). Pass A stashes its
// last tile's exp'd S into Ps (wave-private); pass B's first iteration skips
// computeS and emits aw by coalesced Ps read-back (per-row invl via Ls).
template <int CAUSAL>
__global__ __launch_bounds__(512, 4) void k_attn_fused(
    const u16* __restrict__ qh, const u16* __restrict__ kh,
    const u16* __restrict__ vtg, const float* __restrict__ pmask,
    float* __restrict__ aw, u16* __restrict__ ctx) {
  __shared__ u16 Kt[2][128 * 64];  // [buf][key][dh] swizzled, 32 KB
  __shared__ u16 Vs[64 * 128];     // [d][key]  swizzled, 16 KB
  __shared__ u16 Ps[128 * 128];    // [q][key]  swizzled, wave-private, 32 KB
  __shared__ float Ls[128];        // per-row invl broadcast

  const int jb = blockIdx.x;
  const int lo = jb & 255;
  const int bh = lo & 127;
  const int sel = lo >> 7;
  const int bx = (jb >> 8) == 0 ? sel : 3 - sel;
  const int b = bh >> 3, h = bh & 7;
  const int brow = bx * 128;
  const int tid = threadIdx.x, lane = tid & 63, wid = tid >> 6;
  const int l15 = lane & 15, g4 = lane >> 4;
  const u16* Q = qh + (size_t)bh * NSQ * NDH;
  const u16* Kg = kh + (size_t)bh * NSE * NDH;
  const u16* Vg = vtg + (size_t)bh * NDH * NSE;
  float* awp = aw + (size_t)bh * NSQ * NSE;

  const int krow = wid * 8 + (lane >> 3);            // 0..63
  const int ksw = ((lane & 7) ^ (krow & 7)) * 8;     // K src swizzle
  const int vsw = (l15 ^ ((wid * 4 + g4) & 7)) * 8;  // V src swizzle

  bf16x8 qf[2];
#pragma unroll
  for (int kk = 0; kk < 2; ++kk)
    qf[kk] = *(const bf16x8*)(Q + (size_t)(brow + wid * 16 + l15) * NDH +
                              kk * 32 + g4 * 8);

  const int ntile = CAUSAL ? bx + 1 : 4;

  auto stage_k = [&](int kb, int buf) {
#pragma unroll
    for (int v = 0; v < 2; ++v)
      gl_lds16(Kg + (size_t)(kb + v * 64 + krow) * NDH + ksw,
               Kt[buf] + (v * 64 + wid * 8) * 64);
  };
  auto stage_v = [&](int kb) {
#pragma unroll
    for (int v = 0; v < 2; ++v) {
      const int d = v * 32 + wid * 4 + g4;
      gl_lds16(Vg + (size_t)d * NSE + kb + vsw, Vs + (v * 32 + wid * 4) * 128);
    }
  };
  auto computeS = [&](int kb, int buf, f32x4(&acc)[8]) {
    const u16* kt = Kt[buf];
#pragma unroll
    for (int kk = 0; kk < 2; ++kk) {
      bf16x8 kf[8];
#pragma unroll
      for (int n = 0; n < 8; ++n) {
        const int kr = n * 16 + l15;
        kf[n] = *(const bf16x8*)(kt + kr * 64 + ((kk * 32 + g4 * 8) ^ ((kr & 7) << 3)));
      }
#pragma unroll
      for (int n = 0; n < 8; ++n)
        acc[n] = __builtin_amdgcn_mfma_f32_16x16x32_bf16(qf[kk], kf[n], acc[n], 0, 0, 0);
    }
    if (!CAUSAL) {
      float pm[8];
#pragma unroll
      for (int n = 0; n < 8; ++n)
        pm[n] = pmask[b * NSE + kb + n * 16 + l15] * (-1e9f);
#pragma unroll
      for (int n = 0; n < 8; ++n)
#pragma unroll
        for (int j = 0; j < 4; ++j)
          acc[n][j] = fminf(acc[n][j] * 0.125f, 60.0f) + pm[n];
    } else {
#pragma unroll
      for (int n = 0; n < 8; ++n) {
        const int key = kb + n * 16 + l15;
#pragma unroll
        for (int j = 0; j < 4; ++j) {
          const int qrow = brow + wid * 16 + g4 * 4 + j;
          acc[n][j] = (key > qrow) ? -1e9f : fminf(acc[n][j] * 0.125f, 60.0f);
        }
      }
    }
  };

  // ---- pass A: row sums (max-free); K dbuf, 1 barrier/tile; last tile's
  //      exp'd S stashed (unnormalized bf16) into Ps ----
  float l4[4] = {0.f, 0.f, 0.f, 0.f};
  stage_k(0, 0);
  __syncthreads();
  for (int t = 0; t < ntile; ++t) {
    const int cur = t & 1;
    if (t + 1 < ntile) stage_k((t + 1) * 128, cur ^ 1);  // ages under computeS
    f32x4 acc[8] = {};
    computeS(t * 128, cur, acc);
#pragma unroll
    for (int n = 0; n < 8; ++n)
#pragma unroll
      for (int j = 0; j < 4; ++j) acc[n][j] = __expf(acc[n][j]);
#pragma unroll
    for (int j = 0; j < 4; ++j) {
      float s = 0.f;
#pragma unroll
      for (int n = 0; n < 8; ++n) s += acc[n][j];
#pragma unroll
      for (int o = 1; o < 16; o <<= 1) s += __shfl_xor(s, o, 64);
      l4[j] += s;
    }
    if (t == ntile - 1) {
#pragma unroll
      for (int n = 0; n < 8; ++n) {
        const int col = n * 16 + l15;
#pragma unroll
        for (int j = 0; j < 4; ++j) {
          const int rl = wid * 16 + g4 * 4 + j;
          Ps[rl * 128 + (col ^ ((rl & 7) << 3))] = f2b(acc[n][j]);
        }
      }
    }
    __syncthreads();  // drain prefetch; all waves done with Kt[cur]
  }
  float invl[4];
#pragma unroll
  for (int j = 0; j < 4; ++j) {
    invl[j] = 1.0f / l4[j];
    if (l15 == 0) Ls[wid * 16 + g4 * 4 + j] = invl[j];  // wave-private rows
  }

  // ---- pass B: reversed; first tile reuses pass-A stash (no computeS) ----
  f32x4 apv[4] = {};
  for (int t = ntile - 1; t >= 0; --t) {
    const int kb = t * 128;
    const int cur = t & 1;
    if (t > 0) stage_k((t - 1) * 128, cur ^ 1);  // ages under compute
    stage_v(kb);                                 // ages under compute
    if (t != ntile - 1) {
      f32x4 acc[8] = {};
      computeS(kb, cur, acc);
      __syncthreads();  // drain V(t)+K(t-1); all waves done with Kt[cur]
#pragma unroll
      for (int n = 0; n < 8; ++n) {
        const int col = n * 16 + l15;
#pragma unroll
        for (int j = 0; j < 4; ++j) {
          const int rl = wid * 16 + g4 * 4 + j;
          const float pu = __expf(acc[n][j]);
          awp[(size_t)(brow + rl) * NSE + kb + col] = pu * invl[j];
          Ps[rl * 128 + (col ^ ((rl & 7) << 3))] = f2b(pu);
        }
      }
    } else {
      __syncthreads();  // drain V + K prefetch
      // aw from pass-A stash: coalesced 512B stores per quarter-wave row
#pragma unroll
      for (int i = 0; i < 4; ++i) {
        const int rl = wid * 16 + i * 4 + g4;
        const int cb = l15 * 8;
        const uint4 pk = *(const uint4*)(Ps + rl * 128 + (cb ^ ((rl & 7) << 3)));
        const float il = Ls[rl];
        float* dst = awp + (size_t)(brow + rl) * NSE + kb + cb;
        *(float4*)dst = make_float4(b2f(pk.x & 0xffffu) * il, b2f(pk.x >> 16) * il,
                                    b2f(pk.y & 0xffffu) * il, b2f(pk.y >> 16) * il);
        *(float4*)(dst + 4) =
            make_float4(b2f(pk.z & 0xffffu) * il, b2f(pk.z >> 16) * il,
                        b2f(pk.w & 0xffffu) * il, b2f(pk.w >> 16) * il);
      }
    }
    // PV on UNNORMALIZED P: reads only this wave's Ps rows -> no barrier
#pragma unroll
    for (int kk = 0; kk < 4; ++kk) {
      const int qr = wid * 16 + l15;
      bf16x8 pa =
          *(const bf16x8*)(Ps + qr * 128 + ((kk * 32 + g4 * 8) ^ ((qr & 7) << 3)));
      bf16x8 vb[4];
#pragma unroll
      for (int n = 0; n < 4; ++n) {
        const int d = n * 16 + l15;
        vb[n] = *(const bf16x8*)(Vs + d * 128 + ((kk * 32 + g4 * 8) ^ ((d & 7) << 3)));
      }
#pragma unroll
      for (int n = 0; n < 4; ++n)
        apv[n] = __builtin_amdgcn_mfma_f32_16x16x32_bf16(pa, vb[n], apv[n], 0, 0, 0);
    }
    __syncthreads();  // all waves done with Vs/Ps before next tile overwrites
  }

  if (CAUSAL) {
    const float4 z4 = make_float4(0.f, 0.f, 0.f, 0.f);
    for (int t = ntile; t < 4; ++t) {
      const int r = tid >> 2, c0 = t * 128 + (tid & 3) * 32;
      float4* p = (float4*)(awp + (size_t)(brow + r) * NSE + c0);
#pragma unroll
      for (int i = 0; i < 8; ++i) p[i] = z4;
    }
  }

  // ctx epilogue: normalize apv here (each output row has one invl)
#pragma unroll
  for (int n = 0; n < 4; ++n) {
    const int d = n * 16 + l15;
#pragma unroll
    for (int j = 0; j < 4; ++j) {
      const int r = brow + wid * 16 + g4 * 4 + j;
      ctx[((size_t)(b * NSQ + r)) * ND + h * NDH + d] = f2b(apv[n][j] * invl[j]);
    }
  }
}

// ---------------- residual + LayerNorm (one wave per 512-row) ------------------
template <int B_BF16, int OUT_F32>
__global__ __launch_bounds__(256) void k_res_ln(const u16* __restrict__ a,
                                                const void* __restrict__ bsrc,
                                                const float* __restrict__ g,
                                                const float* __restrict__ bet,
                                                void* __restrict__ outp) {
  const int row = blockIdx.x * 4 + (threadIdx.x >> 6);
  const int lane = threadIdx.x & 63;
  const size_t base = (size_t)row * 512 + lane * 8;
  float s[8];
  {
    uint4 av = *(const uint4*)(a + base);
    s[0] = b2f(av.x & 0xffffu); s[1] = b2f(av.x >> 16);
    s[2] = b2f(av.y & 0xffffu); s[3] = b2f(av.y >> 16);
    s[4] = b2f(av.z & 0xffffu); s[5] = b2f(av.z >> 16);
    s[6] = b2f(av.w & 0xffffu); s[7] = b2f(av.w >> 16);
  }
  if (B_BF16) {
    uint4 bv = *(const uint4*)((const u16*)bsrc + base);
    s[0] += b2f(bv.x & 0xffffu); s[1] += b2f(bv.x >> 16);
    s[2] += b2f(bv.y & 0xffffu); s[3] += b2f(bv.y >> 16);
    s[4] += b2f(bv.z & 0xffffu); s[5] += b2f(bv.z >> 16);
    s[6] += b2f(bv.w & 0xffffu); s[7] += b2f(bv.w >> 16);
  } else {
    const float* bp = (const float*)bsrc + base;
    float4 b0 = *(const float4*)bp, b1 = *(const float4*)(bp + 4);
    s[0] += b0.x; s[1] += b0.y; s[2] += b0.z; s[3] += b0.w;
    s[4] += b1.x; s[5] += b1.y; s[6] += b1.z; s[7] += b1.w;
  }
  float sum = 0.f;
#pragma unroll
  for (int i = 0; i < 8; ++i) sum += s[i];
#pragma unroll
  for (int o = 1; o < 64; o <<= 1) sum += __shfl_xor(sum, o, 64);
  const float mu = sum * (1.0f / 512.0f);
  float vs = 0.f;
#pragma unroll
  for (int i = 0; i < 8; ++i) {
    const float d = s[i] - mu;
    vs += d * d;
  }
#pragma unroll
  for (int o = 1; o < 64; o <<= 1) vs += __shfl_xor(vs, o, 64);
  const float rs = rsqrtf(vs * (1.0f / 512.0f) + 1e-6f);
  float y[8];
#pragma unroll
  for (int i = 0; i < 8; ++i) {
    const int c = lane * 8 + i;
    y[i] = (s[i] - mu) * rs * g[c] + bet[c];
  }
  if (OUT_F32) {
    float* op = (float*)outp + base;
    *(float4*)op = make_float4(y[0], y[1], y[2], y[3]);
    *(float4*)(op + 4) = make_float4(y[4], y[5], y[6], y[7]);
  } else {
    uint4 o;
    o.x = (uint32_t)f2b(y[0]) | ((uint32_t)f2b(y[1]) << 16);
    o.y = (uint32_t)f2b(y[2]) | ((uint32_t)f2b(y[3]) << 16);
    o.z = (uint32_t)f2b(y[4]) | ((uint32_t)f2b(y[5]) << 16);
    o.w = (uint32_t)f2b(y[6]) | ((uint32_t)f2b(y[7]) << 16);
    *(uint4*)((u16*)outp + base) = o;
  }
}

extern "C" void kernel_launch(void* const* d_in, const int* in_sizes, int n_in,
                              void* d_out, int out_size, void* d_ws, size_t ws_size,
                              hipStream_t stream) {
  (void)in_sizes; (void)n_in; (void)out_size; (void)ws_size;
  const float* x = (const float*)d_in[0];
  const float* enc_fc = (const float*)d_in[1];
  const float* enc_ff = (const float*)d_in[2];
  const float* pmask = (const float*)d_in[4];
  const float* w_m1[4] = {(const float*)d_in[5], (const float*)d_in[7],
                          (const float*)d_in[9], (const float*)d_in[11]};
  const float* b_m1[4] = {(const float*)d_in[6], (const float*)d_in[8],
                          (const float*)d_in[10], (const float*)d_in[12]};
  const float* w_m2[4] = {(const float*)d_in[13], (const float*)d_in[15],
                          (const float*)d_in[17], (const float*)d_in[19]};
  const float* b_m2[4] = {(const float*)d_in[14], (const float*)d_in[16],
                          (const float*)d_in[18], (const float*)d_in[20]};
  const float* ffn_w1 = (const float*)d_in[21];
  const float* ffn_b1 = (const float*)d_in[22];
  const float* ffn_w2 = (const float*)d_in[23];
  const float* ffn_b2 = (const float*)d_in[24];
  const float* ln_g[3] = {(const float*)d_in[25], (const float*)d_in[27],
                          (const float*)d_in[29]};
  const float* ln_b[3] = {(const float*)d_in[26], (const float*)d_in[28],
                          (const float*)d_in[30]};

  char* ws = (char*)d_ws;
  const size_t SZB = (size_t)8192 * 512 * 2;  // 8 MiB bf16 activation buffer
  u16* xb = (u16*)(ws + 0 * SZB);
  u16* fcb = (u16*)(ws + 1 * SZB);
  u16* ffb = (u16*)(ws + 2 * SZB);
  u16* qh = (u16*)(ws + 3 * SZB);
  u16* kh = (u16*)(ws + 4 * SZB);
  u16* vt = (u16*)(ws + 5 * SZB);
  u16* ctx = (u16*)(ws + 6 * SZB);
  u16* ao = (u16*)(ws + 7 * SZB);
  u16* out1 = (u16*)(ws + 8 * SZB);
  u16* out2 = (u16*)(ws + 9 * SZB);
  u16* ffv = (u16*)(ws + 10 * SZB);
  u16* ff1 = (u16*)(ws + 11 * SZB);  // 32 MiB
  u16* wts = (u16*)(ws + 11 * SZB + (size_t)8192 * 2048 * 2);
  u16 *wt_m1[4], *wt_m2[4];
  for (int i = 0; i < 4; ++i) {
    wt_m1[i] = wts + (size_t)i * 262144;
    wt_m2[i] = wts + (size_t)(4 + i) * 262144;
  }
  u16* w1t = wts + (size_t)8 * 262144;  // [2048,512]
  u16* w2t = w1t + (size_t)2048 * 512;  // [512,2048]

  float* out3 = (float*)d_out;
  float* aw1 = out3 + (size_t)NB * NSQ * ND;
  float* aw2 = aw1 + (size_t)NB * NH * NSQ * NSQ;

  // prep: single dispatch (casts + all weight transposes)
  Prep pr;
  pr.x = x; pr.fc = enc_fc; pr.ff = enc_ff;
  pr.xb = xb; pr.fcb = fcb; pr.ffb = ffb;
  for (int i = 0; i < 4; ++i) {
    pr.w8[i] = w_m1[i]; pr.o8[i] = wt_m1[i];
    pr.w8[4 + i] = w_m2[i]; pr.o8[4 + i] = wt_m2[i];
  }
  pr.w1 = ffn_w1; pr.w1t = w1t;
  pr.w2 = ffn_w2; pr.w2t = w2t;
  k_prep<<<10240, 256, 0, stream>>>(pr);

  // MHA1 (self, causal)
  QKV q1 = {{xb, xb, xb},
            {wt_m1[0], wt_m1[1], wt_m1[2]},
            {b_m1[0], b_m1[1], b_m1[2]},
            {qh, kh, vt}};
  k_gemm_qkv<<<dim3(64, 4, 3), 256, 0, stream>>>(q1);
  k_attn_fused<1><<<512, 512, 0, stream>>>(qh, kh, vt, nullptr, aw1, ctx);
  k_gemm<64, EPI_GELU><<<dim3(128, 4), 256, 0, stream>>>(ctx, wt_m1[3], b_m1[3], ao, 512, 512);
  k_res_ln<0, 0><<<2048, 256, 0, stream>>>(ao, x, ln_g[0], ln_b[0], out1);
  // MHA2 (cross, padding mask): q=out1, k=enc_fc, v=enc_ff
  QKV q2 = {{out1, fcb, ffb},
            {wt_m2[0], wt_m2[1], wt_m2[2]},
            {b_m2[0], b_m2[1], b_m2[2]},
            {qh, kh, vt}};
  k_gemm_qkv<<<dim3(64, 4, 3), 256, 0, stream>>>(q2);
  k_attn_fused<0><<<512, 512, 0, stream>>>(qh, kh, vt, pmask, aw2, ctx);
  k_gemm<64, EPI_GELU><<<dim3(128, 4), 256, 0, stream>>>(ctx, wt_m2[3], b_m2[3], ao, 512, 512);
  k_res_ln<1, 0><<<2048, 256, 0, stream>>>(ao, out1, ln_g[1], ln_b[1], out2);
  // FFN
  k_gemm<128, EPI_RELU><<<dim3(64, 16), 256, 0, stream>>>(out2, w1t, ffn_b1, ff1, 512, 2048);
  k_gemm<64, EPI_NONE><<<dim3(128, 4), 256, 0, stream>>>(ff1, w2t, ffn_b2, ffv, 2048, 512);
  k_res_ln<1, 1><<<2048, 256, 0, stream>>>(ffv, out2, ln_g[2], ln_b[2], (void*)d_out);
}